// Round 11
// baseline (454.057 us; speedup 1.0000x reference)
//
#include <hip/hip_runtime.h>
#include <hip/hip_bf16.h>
#include <math.h>

#define N_NODES 100000
#define N_EDGES 1600000
#define IN_CH 128
#define OUT_CH 128
#define EDGE_DIM 6
#define STATE_DIM 5
#define XS_DIM 133          // IN_CH + STATE_DIM
#define KPAD 160            // 5 k-steps of 32
#define NKSTEP 5
#define ASTRIDE 168         // LDS row stride (bf16 elems)
#define NBLK 391            // ceil(N_NODES/256)
#define N_CHUNKS 25000      // N_EDGES / 64  (exact)
#define NGB 1563            // gemm blocks = ceil(N_NODES/64)

typedef short s16x8 __attribute__((ext_vector_type(8)));
typedef float f32x4 __attribute__((ext_vector_type(4)));
typedef float f32x2 __attribute__((ext_vector_type(2)));
typedef unsigned u32x4 __attribute__((ext_vector_type(4)));

static __device__ __forceinline__ unsigned short f2bf(float f) {
    __hip_bfloat16 h = __float2bfloat16(f);   // RNE
    return *reinterpret_cast<unsigned short*>(&h);
}
static __device__ __forceinline__ float bflo(unsigned u) {   // low bf16 -> f32
    return __uint_as_float(u << 16);
}
static __device__ __forceinline__ float bfhi(unsigned u) {   // high bf16 -> f32
    return __uint_as_float(u & 0xffff0000u);
}

// ---------------------------------------------------------------------------
// repack_zero: W repack + cnt zeroing folded in. 80 blocks x 64.
// ---------------------------------------------------------------------------
__global__ __launch_bounds__(64) void repack_zero(
    const float* __restrict__ Wneg, const float* __restrict__ Wroot,
    unsigned short* __restrict__ Pneg, unsigned short* __restrict__ Proot,
    int* __restrict__ cnt)
{
    int b = blockIdx.x;
    int lane = threadIdx.x;

    // zero cnt: 5120 threads, 100000 ints -> ~20 per thread, coalesced
    for (int i = b * 64 + lane; i < N_NODES; i += 80 * 64) cnt[i] = 0;

    int mat = b / 40, r = b % 40;
    int kk = r / 8, nt = r % 8;
    const float* W = mat ? Wroot : Wneg;
    unsigned short* P = mat ? Proot : Pneg;
    int n = nt * 16 + (lane & 15);
    int kb = kk * 32 + (lane >> 4) * 8;
    unsigned short v[8];
#pragma unroll
    for (int j = 0; j < 8; ++j) {
        int k = kb + j;
        v[j] = (k < XS_DIM) ? f2bf(W[k * 128 + n]) : (unsigned short)0;
    }
    *(s16x8*)(P + ((size_t)(kk * 8 + nt) * 64 + lane) * 8) = *(s16x8*)v;
}

// ---------------------------------------------------------------------------
// histogram_rank: count edges per dst AND record each edge's arrival rank
// (the atomicAdd return value). rank[e] lets scatter compute its slot as
// off[dst]+rank[e] with NO atomic.
// ---------------------------------------------------------------------------
__global__ __launch_bounds__(256) void histogram_rank(const int* __restrict__ idx,
                                                      int* __restrict__ cnt,
                                                      int* __restrict__ rank) {
    int e = blockIdx.x * 256 + threadIdx.x;
    if (e < N_EDGES) {
        int d = __builtin_nontemporal_load(idx + e);
        int r = atomicAdd(&cnt[d], 1);
        __builtin_nontemporal_store(r, rank + e);
    }
}

// ---------------------------------------------------------------------------
// scan_all: MERGED scan_block_sums + scan_final2 (one dispatch, one fewer
// launch boundary, no bsum buffer). Each block computes its own prefix
// bpre = sum(cnt[0 .. bid*256)) by coalesced grid-stride sum — total ~78 MB
// of L2-resident reads across the grid (~2-3us), cheaper than a dispatch
// boundary (~10-12us). Then in-block exclusive scan -> off, chunk_node fill.
// ---------------------------------------------------------------------------
__global__ __launch_bounds__(256) void scan_all(const int* __restrict__ cnt,
                                                int* __restrict__ off,
                                                int* __restrict__ chunk_node) {
    __shared__ int wsum[4];
    __shared__ int bpre_s;
    int tid = threadIdx.x, lane = tid & 63, wid = tid >> 6;
    int bid = blockIdx.x;

    // block prefix = sum(cnt[0..bid*256)), coalesced: lane t reads t, t+256,...
    int pre = 0;
    int lim = bid * 256;
    for (int j = tid; j < lim; j += 256) pre += cnt[j];
#pragma unroll
    for (int d = 32; d > 0; d >>= 1) pre += __shfl_down(pre, d);
    if (lane == 0) wsum[wid] = pre;
    __syncthreads();
    if (tid == 0) bpre_s = wsum[0] + wsum[1] + wsum[2] + wsum[3];
    __syncthreads();
    int bpre = bpre_s;

    int i = bid * 256 + tid;
    int v = (i < N_NODES) ? cnt[i] : 0;
    int x = v;
#pragma unroll
    for (int d = 1; d < 64; d <<= 1) {
        int t = __shfl_up(x, d);
        if (lane >= d) x += t;
    }
    __syncthreads();                   // all reads of phase-1 wsum complete
    if (lane == 63) wsum[wid] = x;
    __syncthreads();
    int wpre = 0;
#pragma unroll
    for (int j = 0; j < 4; ++j) wpre += (j < wid) ? wsum[j] : 0;
    int excl = bpre + wpre + x - v;
    if (i < N_NODES) {
        off[i] = excl;
        if (v > 0) {
            int end = excl + v;
            for (int c = (excl + 63) >> 6; (c << 6) < end; ++c)
                chunk_node[c] = i;     // chunk start 64c lies inside [excl,end)
        }
    }
}

// ---------------------------------------------------------------------------
// gemm_scatter v3 (unchanged from R10): role-split dispatch.
//  Scatter: slot = off[dst] + rank[e] — atomic-free.
//  GEMM: B fragments staged per-kk into LDS, ds_read_b128 consumption.
// ---------------------------------------------------------------------------
__global__ __launch_bounds__(256) void gemm_scatter(
    const float* __restrict__ x, const float* __restrict__ gs,
    const unsigned short* __restrict__ Pneg, const unsigned short* __restrict__ Proot,
    const float* __restrict__ bneg, const float* __restrict__ broot,
    __hip_bfloat16* __restrict__ Yb, float* __restrict__ out,
    const int* __restrict__ idx, const float* __restrict__ ea,
    const int* __restrict__ off, const int* __restrict__ rank,
    uint4* __restrict__ pay)
{
    __shared__ unsigned short Alds[64 * ASTRIDE];        // 21504 B
    __shared__ unsigned short Blds[2 * 8 * 64 * 8];      // 16384 B (per-kk slice)
    const int bid = blockIdx.x;
    const int role = bid & 1;
    const int rid  = bid >> 1;
    const int tid  = threadIdx.x;

    if (role == 1) {
        // ---- payload scatter (grid-stride over edges; atomic-free) ----
        for (int e = rid * 256 + tid; e < N_EDGES; e += NGB * 256) {
            int dst = __builtin_nontemporal_load(idx + e);
            int src = __builtin_nontemporal_load(idx + N_EDGES + e);
            int rk  = __builtin_nontemporal_load(rank + e);
            const f32x2* er = (const f32x2*)(ea + (size_t)e * EDGE_DIM);
            f32x2 e01 = __builtin_nontemporal_load(er);
            f32x2 e23 = __builtin_nontemporal_load(er + 1);
            f32x2 e45 = __builtin_nontemporal_load(er + 2);
            unsigned p0 = (unsigned)f2bf(e01.x) | ((unsigned)f2bf(e01.y) << 16);
            unsigned p1 = (unsigned)f2bf(e23.x) | ((unsigned)f2bf(e23.y) << 16);
            unsigned p2 = (unsigned)f2bf(e45.x) | ((unsigned)f2bf(e45.y) << 16);
            int pos = off[dst] + rk;          // L2-resident read, no atomic
            u32x4 pl = { (unsigned)src, p0, p1, p2 };
            __builtin_nontemporal_store(pl, (u32x4*)pay + pos);
        }
        return;
    }

    // ---- node GEMM: 64 nodes, 4 waves ----
    const int lane = tid & 63;
    const int wv   = tid >> 6;
    const int n0   = rid * 64;

#pragma unroll
    for (int i = 0; i < 16; ++i) {
        int row = i * 4 + wv;
        int nn  = min(n0 + row, N_NODES - 1);
        const f32x2 v = __builtin_nontemporal_load(
            (const f32x2*)(x + (size_t)nn * IN_CH) + lane);
        unsigned pk = (unsigned)f2bf(v.x) | ((unsigned)f2bf(v.y) << 16);
        *(unsigned*)(&Alds[row * ASTRIDE + lane * 2]) = pk;   // aligned b32
    }
    // cols 128..159 (gs + zero pad): 64 rows x 16 u32-pairs, 4 per thread
#pragma unroll
    for (int s2 = 0; s2 < 4; ++s2) {
        int slot = tid * 4 + s2;        // 0..1023
        int row  = slot >> 4;
        int cp   = slot & 15;
        int nn   = min(n0 + row, N_NODES - 1);
        int c0   = IN_CH + cp * 2;
        unsigned lo = (c0     < XS_DIM) ? (unsigned)f2bf(gs[(size_t)nn * STATE_DIM + (c0 - IN_CH)])     : 0u;
        unsigned hi = (c0 + 1 < XS_DIM) ? (unsigned)f2bf(gs[(size_t)nn * STATE_DIM + (c0 + 1 - IN_CH)]) : 0u;
        *(unsigned*)(&Alds[row * ASTRIDE + c0]) = lo | (hi << 16);
    }

    f32x4 accN[8], accR[8];
    const f32x4 zero = {0.f, 0.f, 0.f, 0.f};
#pragma unroll
    for (int nt = 0; nt < 8; ++nt) { accN[nt] = zero; accR[nt] = zero; }

    const int m = lane & 15, quad = lane >> 4;
    const unsigned short* arow = Alds + (wv * 16 + m) * ASTRIDE + quad * 8;
    const unsigned short* bl   = Blds + lane * 8;          // (mat,nt) via offset

    for (int kk = 0; kk < NKSTEP; ++kk) {
        __syncthreads();      // kk=0: Alds ready; kk>0: prior Blds consumed
        // stage this kk's B slice: 1024 x 16B chunks, 4 per thread
#pragma unroll
        for (int j = 0; j < 4; ++j) {
            int c = tid * 4 + j;              // 0..1023
            int mat = c >> 9, r = c & 511;    // r = nt*64+lane
            const unsigned short* src =
                (mat ? Proot : Pneg) + ((size_t)(kk * 8) * 64 + r) * 8;
            *(s16x8*)(Blds + (size_t)c * 8) = *(const s16x8*)src;
        }
        __syncthreads();

        s16x8 a = *(const s16x8*)(arow + kk * 32);
#pragma unroll
        for (int nt = 0; nt < 8; ++nt) {
            s16x8 bn = *(const s16x8*)(bl + (size_t)nt * 512);          // mat 0
            accN[nt] = __builtin_amdgcn_mfma_f32_16x16x32_bf16(a, bn, accN[nt], 0, 0, 0);
            s16x8 br = *(const s16x8*)(bl + (size_t)(8 + nt) * 512);    // mat 1
            accR[nt] = __builtin_amdgcn_mfma_f32_16x16x32_bf16(a, br, accR[nt], 0, 0, 0);
        }
    }

#pragma unroll
    for (int nt = 0; nt < 8; ++nt) {
        int col = nt * 16 + m;
        float bn = bneg[col], br = broot[col];
        int rbase = n0 + wv * 16 + quad * 4;
#pragma unroll
        for (int r = 0; r < 4; ++r) {
            int node = rbase + r;
            if (node < N_NODES) {
                Yb[(size_t)node * 128 + col] = __float2bfloat16(accN[nt][r] + bn);
                float v = accR[nt][r] + br;
                out[(size_t)node * 128 + col] = (v > 0.f) ? v : (__expf(v) - 1.f);
            }
        }
    }
}

// ---------------------------------------------------------------------------
// Aggregate, edge-parallel (R6 verbatim — measured best, 121+-2us band):
// ---------------------------------------------------------------------------
__global__ __launch_bounds__(256) void aggregate(
    const uint4* __restrict__ pay,
    const float* __restrict__ Wneg,  // bottom 6 rows at 133*128
    const __hip_bfloat16* __restrict__ Yb,
    const int* __restrict__ off,
    const int* __restrict__ chunk_node,
    float* __restrict__ out)
{
    const int lane = threadIdx.x & 63;
    const int wid  = __builtin_amdgcn_readfirstlane(blockIdx.x * 4 + (threadIdx.x >> 6));
    const int e0   = wid * 64;

    const float2* wb2 = (const float2*)(Wneg + 133 * 128);
    float2 wb[EDGE_DIM];
#pragma unroll
    for (int j = 0; j < EDGE_DIM; ++j) wb[j] = wb2[j * 64 + lane];

    const unsigned* Yu = (const unsigned*)Yb;   // 64 uints per row

    u32x4 pl = __builtin_nontemporal_load((const u32x4*)pay + e0 + lane);
    int src_l = (int)pl.x;
    int ea0 = (int)pl.y, ea1 = (int)pl.z, ea2 = (int)pl.w;

    // wave-uniform segment walk state
    int n   = __builtin_amdgcn_readfirstlane(chunk_node[wid]);
    int nxt = __builtin_amdgcn_readfirstlane((n + 1 < N_NODES) ? off[n + 1] : N_EDGES);

    float accx = 0.f, accy = 0.f;

    // prefetch batches 0 and 1 (16 Y-row loads in flight)
    unsigned yA[8], yB[8];
#pragma unroll
    for (int j = 0; j < 8; ++j) {
        int s = __builtin_amdgcn_readlane(src_l, j);
        yA[j] = Yu[(size_t)s * 64 + lane];
    }
#pragma unroll
    for (int j = 0; j < 8; ++j) {
        int s = __builtin_amdgcn_readlane(src_l, 8 + j);
        yB[j] = Yu[(size_t)s * 64 + lane];
    }

    auto edge_op = [&](unsigned yv, int c, bool last) {
        unsigned a0 = (unsigned)__builtin_amdgcn_readlane(ea0, c);
        unsigned a1 = (unsigned)__builtin_amdgcn_readlane(ea1, c);
        unsigned a2 = (unsigned)__builtin_amdgcn_readlane(ea2, c);
        float f0 = bflo(a0), f1 = bfhi(a0);
        float f2 = bflo(a1), f3 = bfhi(a1);
        float f4 = bflo(a2), f5 = bfhi(a2);
        float tx = bflo(yv), ty = bfhi(yv);
        tx = fmaf(f0, wb[0].x, tx); ty = fmaf(f0, wb[0].y, ty);
        tx = fmaf(f1, wb[1].x, tx); ty = fmaf(f1, wb[1].y, ty);
        tx = fmaf(f2, wb[2].x, tx); ty = fmaf(f2, wb[2].y, ty);
        tx = fmaf(f3, wb[3].x, tx); ty = fmaf(f3, wb[3].y, ty);
        tx = fmaf(f4, wb[4].x, tx); ty = fmaf(f4, wb[4].y, ty);
        tx = fmaf(f5, wb[5].x, tx); ty = fmaf(f5, wb[5].y, ty);
        tx = (tx > 0.f) ? tx : (__expf(tx) - 1.f);
        ty = (ty > 0.f) ? ty : (__expf(ty) - 1.f);
        accx += tx; accy += ty;
        int e = e0 + c;
        bool bend = (e + 1 == nxt);             // uniform -> s_cmp/s_cbranch
        if (last || bend) {
            float* orow = out + ((size_t)n << 7) + (lane << 1);
            atomicAdd(orow,     accx);
            atomicAdd(orow + 1, accy);
            accx = 0.f; accy = 0.f;
            if (!last) {                        // advance to node owning e+1
                n++;
                nxt = __builtin_amdgcn_readfirstlane(
                    (n + 1 < N_NODES) ? off[n + 1] : N_EDGES);
                while (nxt <= e + 1) {          // skip empty nodes (rare)
                    n++;
                    nxt = __builtin_amdgcn_readfirstlane(
                        (n + 1 < N_NODES) ? off[n + 1] : N_EDGES);
                }
            }
        }
    };

    // batches 0..5 with 2-ahead prefetch; tail 6,7 drains
#pragma unroll 1
    for (int q = 0; q < 3; ++q) {
        const int base = q * 16;
        const int pb   = base + 16;             // refill with batch b+2
#pragma unroll
        for (int j = 0; j < 8; ++j) {
            edge_op(yA[j], base + j, false);
            int s = __builtin_amdgcn_readlane(src_l, pb + j);
            yA[j] = Yu[(size_t)s * 64 + lane];
        }
#pragma unroll
        for (int j = 0; j < 8; ++j) {
            edge_op(yB[j], base + 8 + j, false);
            int s = __builtin_amdgcn_readlane(src_l, pb + 8 + j);
            yB[j] = Yu[(size_t)s * 64 + lane];
        }
    }
#pragma unroll
    for (int j = 0; j < 8; ++j) edge_op(yA[j], 48 + j, false);
#pragma unroll
    for (int j = 0; j < 8; ++j) edge_op(yB[j], 56 + j, j == 7);
}

extern "C" void kernel_launch(void* const* d_in, const int* in_sizes, int n_in,
                              void* d_out, int out_size, void* d_ws, size_t ws_size,
                              hipStream_t stream) {
    const float* x     = (const float*)d_in[0];
    const int*   idx   = (const int*)  d_in[1];
    const float* ea    = (const float*)d_in[2];
    const float* gs    = (const float*)d_in[3];
    const float* Wneg  = (const float*)d_in[4];
    const float* bneg  = (const float*)d_in[5];
    const float* Wroot = (const float*)d_in[6];
    const float* broot = (const float*)d_in[7];
    float* out = (float*)d_out;

    // ws layout (16B-aligned sections):
    //   Yb      : N*128 bf16           25.6 MB
    //   cnt/off : N int each            0.8 MB
    //   pay     : E * 16B              25.6 MB
    //   rank    : E * 4B                6.4 MB
    //   Pneg/Proot : 40 KB each
    //   chunk_node : 25000 int         100 KB
    char* w = (char*)d_ws;
    __hip_bfloat16* Yb = (__hip_bfloat16*)w;      w += (size_t)N_NODES * 128 * 2;
    int* cnt  = (int*)w;                          w += (size_t)N_NODES * 4;
    int* off  = (int*)w;                          w += (size_t)N_NODES * 4;
    uint4* pay = (uint4*)w;                       w += (size_t)N_EDGES * 16;
    int* rank = (int*)w;                          w += (size_t)N_EDGES * 4;
    unsigned short* Pneg  = (unsigned short*)w;   w += (size_t)NKSTEP * 8 * 64 * 8 * 2;
    unsigned short* Proot = (unsigned short*)w;   w += (size_t)NKSTEP * 8 * 64 * 8 * 2;
    int* chunk_node = (int*)w;

    const int nb_edges = (N_EDGES + 255) / 256;

    repack_zero<<<80, 64, 0, stream>>>(Wneg, Wroot, Pneg, Proot, cnt);
    histogram_rank<<<nb_edges, 256, 0, stream>>>(idx, cnt, rank);
    scan_all<<<NBLK, 256, 0, stream>>>(cnt, off, chunk_node);
    gemm_scatter<<<2 * NGB, 256, 0, stream>>>(
        x, gs, Pneg, Proot, bneg, broot, Yb, out, idx, ea, off, rank, pay);
    aggregate<<<N_CHUNKS / 4, 256, 0, stream>>>(pay, Wneg, Yb, off, chunk_node, out);
}

// Round 12
// 407.519 us; speedup vs baseline: 1.1142x; 1.1142x over previous
//
#include <hip/hip_runtime.h>
#include <hip/hip_bf16.h>
#include <math.h>

#define N_NODES 100000
#define N_EDGES 1600000
#define IN_CH 128
#define OUT_CH 128
#define EDGE_DIM 6
#define STATE_DIM 5
#define XS_DIM 133          // IN_CH + STATE_DIM
#define KPAD 160            // 5 k-steps of 32
#define NKSTEP 5
#define ASTRIDE 168         // LDS row stride (bf16 elems)
#define NBLK 391            // ceil(N_NODES/256)
#define N_CHUNKS 25000      // N_EDGES / 64  (exact)
#define NGB 1563            // gemm blocks = ceil(N_NODES/64)

typedef short s16x8 __attribute__((ext_vector_type(8)));
typedef float f32x4 __attribute__((ext_vector_type(4)));
typedef float f32x2 __attribute__((ext_vector_type(2)));
typedef unsigned u32x4 __attribute__((ext_vector_type(4)));

static __device__ __forceinline__ unsigned short f2bf(float f) {
    __hip_bfloat16 h = __float2bfloat16(f);   // RNE
    return *reinterpret_cast<unsigned short*>(&h);
}
static __device__ __forceinline__ float bflo(unsigned u) {   // low bf16 -> f32
    return __uint_as_float(u << 16);
}
static __device__ __forceinline__ float bfhi(unsigned u) {   // high bf16 -> f32
    return __uint_as_float(u & 0xffff0000u);
}

// ---------------------------------------------------------------------------
// repack_zero: W repack + cnt zeroing folded in. 80 blocks x 64.
// ---------------------------------------------------------------------------
__global__ __launch_bounds__(64) void repack_zero(
    const float* __restrict__ Wneg, const float* __restrict__ Wroot,
    unsigned short* __restrict__ Pneg, unsigned short* __restrict__ Proot,
    int* __restrict__ cnt)
{
    int b = blockIdx.x;
    int lane = threadIdx.x;

    // zero cnt: 5120 threads, 100000 ints -> ~20 per thread, coalesced
    for (int i = b * 64 + lane; i < N_NODES; i += 80 * 64) cnt[i] = 0;

    int mat = b / 40, r = b % 40;
    int kk = r / 8, nt = r % 8;
    const float* W = mat ? Wroot : Wneg;
    unsigned short* P = mat ? Proot : Pneg;
    int n = nt * 16 + (lane & 15);
    int kb = kk * 32 + (lane >> 4) * 8;
    unsigned short v[8];
#pragma unroll
    for (int j = 0; j < 8; ++j) {
        int k = kb + j;
        v[j] = (k < XS_DIM) ? f2bf(W[k * 128 + n]) : (unsigned short)0;
    }
    *(s16x8*)(P + ((size_t)(kk * 8 + nt) * 64 + lane) * 8) = *(s16x8*)v;
}

// ---------------------------------------------------------------------------
// histogram_rank: count edges per dst AND record each edge's arrival rank
// (the atomicAdd return value). rank[e] lets scatter compute its slot as
// off[dst]+rank[e] with NO atomic.
// ---------------------------------------------------------------------------
__global__ __launch_bounds__(256) void histogram_rank(const int* __restrict__ idx,
                                                      int* __restrict__ cnt,
                                                      int* __restrict__ rank) {
    int e = blockIdx.x * 256 + threadIdx.x;
    if (e < N_EDGES) {
        int d = __builtin_nontemporal_load(idx + e);
        int r = atomicAdd(&cnt[d], 1);
        __builtin_nontemporal_store(r, rank + e);
    }
}

// ---------------------------------------------------------------------------
// Two-kernel scan (R10 measured-best; R11's merged scan_all regressed 45us —
// its O(bid) grid-stride prefix at 391-block occupancy was latency-bound).
// ---------------------------------------------------------------------------
__global__ __launch_bounds__(256) void scan_block_sums(const int* __restrict__ cnt,
                                                       int* __restrict__ bsum) {
    __shared__ int ws[4];
    int tid = threadIdx.x, lane = tid & 63, wid = tid >> 6;
    int i = blockIdx.x * 256 + tid;
    int v = (i < N_NODES) ? cnt[i] : 0;
#pragma unroll
    for (int d = 32; d > 0; d >>= 1) v += __shfl_down(v, d);
    if (lane == 0) ws[wid] = v;
    __syncthreads();
    if (tid == 0) bsum[blockIdx.x] = ws[0] + ws[1] + ws[2] + ws[3];
}

// scan_final2: in-block 391-entry bsum prefix (NBLK ints only — cheap),
// node exclusive scan -> off, chunk_node fill.
__global__ __launch_bounds__(256) void scan_final2(const int* __restrict__ cnt,
                                                   const int* __restrict__ bsum,
                                                   int* __restrict__ off,
                                                   int* __restrict__ chunk_node) {
    __shared__ int wsum[4];
    __shared__ int bpre_s;
    int tid = threadIdx.x, lane = tid & 63, wid = tid >> 6;
    int bid = blockIdx.x;

    // block prefix = sum(bsum[0..bid))
    int pre = 0;
    for (int j = tid; j < bid; j += 256) pre += bsum[j];
#pragma unroll
    for (int d = 32; d > 0; d >>= 1) pre += __shfl_down(pre, d);
    if (lane == 0) wsum[wid] = pre;
    __syncthreads();
    if (tid == 0) bpre_s = wsum[0] + wsum[1] + wsum[2] + wsum[3];
    __syncthreads();
    int bpre = bpre_s;

    int i = bid * 256 + tid;
    int v = (i < N_NODES) ? cnt[i] : 0;
    int x = v;
#pragma unroll
    for (int d = 1; d < 64; d <<= 1) {
        int t = __shfl_up(x, d);
        if (lane >= d) x += t;
    }
    if (lane == 63) wsum[wid] = x;     // safe: all reads of phase-1 wsum done
    __syncthreads();
    int wpre = 0;
#pragma unroll
    for (int j = 0; j < 4; ++j) wpre += (j < wid) ? wsum[j] : 0;
    int excl = bpre + wpre + x - v;
    if (i < N_NODES) {
        off[i] = excl;
        if (v > 0) {
            int end = excl + v;
            for (int c = (excl + 63) >> 6; (c << 6) < end; ++c)
                chunk_node[c] = i;     // chunk start 64c lies inside [excl,end)
        }
    }
}

// ---------------------------------------------------------------------------
// gemm_scatter v3 (R10 verbatim): role-split dispatch.
//  Scatter: slot = off[dst] + rank[e] — atomic-free.
//  GEMM: B fragments staged per-kk into LDS, ds_read_b128 consumption.
// ---------------------------------------------------------------------------
__global__ __launch_bounds__(256) void gemm_scatter(
    const float* __restrict__ x, const float* __restrict__ gs,
    const unsigned short* __restrict__ Pneg, const unsigned short* __restrict__ Proot,
    const float* __restrict__ bneg, const float* __restrict__ broot,
    __hip_bfloat16* __restrict__ Yb, float* __restrict__ out,
    const int* __restrict__ idx, const float* __restrict__ ea,
    const int* __restrict__ off, const int* __restrict__ rank,
    uint4* __restrict__ pay)
{
    __shared__ unsigned short Alds[64 * ASTRIDE];        // 21504 B
    __shared__ unsigned short Blds[2 * 8 * 64 * 8];      // 16384 B (per-kk slice)
    const int bid = blockIdx.x;
    const int role = bid & 1;
    const int rid  = bid >> 1;
    const int tid  = threadIdx.x;

    if (role == 1) {
        // ---- payload scatter (grid-stride over edges; atomic-free) ----
        for (int e = rid * 256 + tid; e < N_EDGES; e += NGB * 256) {
            int dst = __builtin_nontemporal_load(idx + e);
            int src = __builtin_nontemporal_load(idx + N_EDGES + e);
            int rk  = __builtin_nontemporal_load(rank + e);
            const f32x2* er = (const f32x2*)(ea + (size_t)e * EDGE_DIM);
            f32x2 e01 = __builtin_nontemporal_load(er);
            f32x2 e23 = __builtin_nontemporal_load(er + 1);
            f32x2 e45 = __builtin_nontemporal_load(er + 2);
            unsigned p0 = (unsigned)f2bf(e01.x) | ((unsigned)f2bf(e01.y) << 16);
            unsigned p1 = (unsigned)f2bf(e23.x) | ((unsigned)f2bf(e23.y) << 16);
            unsigned p2 = (unsigned)f2bf(e45.x) | ((unsigned)f2bf(e45.y) << 16);
            int pos = off[dst] + rk;          // L2-resident read, no atomic
            u32x4 pl = { (unsigned)src, p0, p1, p2 };
            __builtin_nontemporal_store(pl, (u32x4*)pay + pos);
        }
        return;
    }

    // ---- node GEMM: 64 nodes, 4 waves ----
    const int lane = tid & 63;
    const int wv   = tid >> 6;
    const int n0   = rid * 64;

#pragma unroll
    for (int i = 0; i < 16; ++i) {
        int row = i * 4 + wv;
        int nn  = min(n0 + row, N_NODES - 1);
        const f32x2 v = __builtin_nontemporal_load(
            (const f32x2*)(x + (size_t)nn * IN_CH) + lane);
        unsigned pk = (unsigned)f2bf(v.x) | ((unsigned)f2bf(v.y) << 16);
        *(unsigned*)(&Alds[row * ASTRIDE + lane * 2]) = pk;   // aligned b32
    }
    // cols 128..159 (gs + zero pad): 64 rows x 16 u32-pairs, 4 per thread
#pragma unroll
    for (int s2 = 0; s2 < 4; ++s2) {
        int slot = tid * 4 + s2;        // 0..1023
        int row  = slot >> 4;
        int cp   = slot & 15;
        int nn   = min(n0 + row, N_NODES - 1);
        int c0   = IN_CH + cp * 2;
        unsigned lo = (c0     < XS_DIM) ? (unsigned)f2bf(gs[(size_t)nn * STATE_DIM + (c0 - IN_CH)])     : 0u;
        unsigned hi = (c0 + 1 < XS_DIM) ? (unsigned)f2bf(gs[(size_t)nn * STATE_DIM + (c0 + 1 - IN_CH)]) : 0u;
        *(unsigned*)(&Alds[row * ASTRIDE + c0]) = lo | (hi << 16);
    }

    f32x4 accN[8], accR[8];
    const f32x4 zero = {0.f, 0.f, 0.f, 0.f};
#pragma unroll
    for (int nt = 0; nt < 8; ++nt) { accN[nt] = zero; accR[nt] = zero; }

    const int m = lane & 15, quad = lane >> 4;
    const unsigned short* arow = Alds + (wv * 16 + m) * ASTRIDE + quad * 8;
    const unsigned short* bl   = Blds + lane * 8;          // (mat,nt) via offset

    for (int kk = 0; kk < NKSTEP; ++kk) {
        __syncthreads();      // kk=0: Alds ready; kk>0: prior Blds consumed
        // stage this kk's B slice: 1024 x 16B chunks, 4 per thread
#pragma unroll
        for (int j = 0; j < 4; ++j) {
            int c = tid * 4 + j;              // 0..1023
            int mat = c >> 9, r = c & 511;    // r = nt*64+lane
            const unsigned short* src =
                (mat ? Proot : Pneg) + ((size_t)(kk * 8) * 64 + r) * 8;
            *(s16x8*)(Blds + (size_t)c * 8) = *(const s16x8*)src;
        }
        __syncthreads();

        s16x8 a = *(const s16x8*)(arow + kk * 32);
#pragma unroll
        for (int nt = 0; nt < 8; ++nt) {
            s16x8 bn = *(const s16x8*)(bl + (size_t)nt * 512);          // mat 0
            accN[nt] = __builtin_amdgcn_mfma_f32_16x16x32_bf16(a, bn, accN[nt], 0, 0, 0);
            s16x8 br = *(const s16x8*)(bl + (size_t)(8 + nt) * 512);    // mat 1
            accR[nt] = __builtin_amdgcn_mfma_f32_16x16x32_bf16(a, br, accR[nt], 0, 0, 0);
        }
    }

#pragma unroll
    for (int nt = 0; nt < 8; ++nt) {
        int col = nt * 16 + m;
        float bn = bneg[col], br = broot[col];
        int rbase = n0 + wv * 16 + quad * 4;
#pragma unroll
        for (int r = 0; r < 4; ++r) {
            int node = rbase + r;
            if (node < N_NODES) {
                Yb[(size_t)node * 128 + col] = __float2bfloat16(accN[nt][r] + bn);
                float v = accR[nt][r] + br;
                out[(size_t)node * 128 + col] = (v > 0.f) ? v : (__expf(v) - 1.f);
            }
        }
    }
}

// ---------------------------------------------------------------------------
// Aggregate, edge-parallel (R6 verbatim — measured best, 121+-2us band):
// ---------------------------------------------------------------------------
__global__ __launch_bounds__(256) void aggregate(
    const uint4* __restrict__ pay,
    const float* __restrict__ Wneg,  // bottom 6 rows at 133*128
    const __hip_bfloat16* __restrict__ Yb,
    const int* __restrict__ off,
    const int* __restrict__ chunk_node,
    float* __restrict__ out)
{
    const int lane = threadIdx.x & 63;
    const int wid  = __builtin_amdgcn_readfirstlane(blockIdx.x * 4 + (threadIdx.x >> 6));
    const int e0   = wid * 64;

    const float2* wb2 = (const float2*)(Wneg + 133 * 128);
    float2 wb[EDGE_DIM];
#pragma unroll
    for (int j = 0; j < EDGE_DIM; ++j) wb[j] = wb2[j * 64 + lane];

    const unsigned* Yu = (const unsigned*)Yb;   // 64 uints per row

    u32x4 pl = __builtin_nontemporal_load((const u32x4*)pay + e0 + lane);
    int src_l = (int)pl.x;
    int ea0 = (int)pl.y, ea1 = (int)pl.z, ea2 = (int)pl.w;

    // wave-uniform segment walk state
    int n   = __builtin_amdgcn_readfirstlane(chunk_node[wid]);
    int nxt = __builtin_amdgcn_readfirstlane((n + 1 < N_NODES) ? off[n + 1] : N_EDGES);

    float accx = 0.f, accy = 0.f;

    // prefetch batches 0 and 1 (16 Y-row loads in flight)
    unsigned yA[8], yB[8];
#pragma unroll
    for (int j = 0; j < 8; ++j) {
        int s = __builtin_amdgcn_readlane(src_l, j);
        yA[j] = Yu[(size_t)s * 64 + lane];
    }
#pragma unroll
    for (int j = 0; j < 8; ++j) {
        int s = __builtin_amdgcn_readlane(src_l, 8 + j);
        yB[j] = Yu[(size_t)s * 64 + lane];
    }

    auto edge_op = [&](unsigned yv, int c, bool last) {
        unsigned a0 = (unsigned)__builtin_amdgcn_readlane(ea0, c);
        unsigned a1 = (unsigned)__builtin_amdgcn_readlane(ea1, c);
        unsigned a2 = (unsigned)__builtin_amdgcn_readlane(ea2, c);
        float f0 = bflo(a0), f1 = bfhi(a0);
        float f2 = bflo(a1), f3 = bfhi(a1);
        float f4 = bflo(a2), f5 = bfhi(a2);
        float tx = bflo(yv), ty = bfhi(yv);
        tx = fmaf(f0, wb[0].x, tx); ty = fmaf(f0, wb[0].y, ty);
        tx = fmaf(f1, wb[1].x, tx); ty = fmaf(f1, wb[1].y, ty);
        tx = fmaf(f2, wb[2].x, tx); ty = fmaf(f2, wb[2].y, ty);
        tx = fmaf(f3, wb[3].x, tx); ty = fmaf(f3, wb[3].y, ty);
        tx = fmaf(f4, wb[4].x, tx); ty = fmaf(f4, wb[4].y, ty);
        tx = fmaf(f5, wb[5].x, tx); ty = fmaf(f5, wb[5].y, ty);
        tx = (tx > 0.f) ? tx : (__expf(tx) - 1.f);
        ty = (ty > 0.f) ? ty : (__expf(ty) - 1.f);
        accx += tx; accy += ty;
        int e = e0 + c;
        bool bend = (e + 1 == nxt);             // uniform -> s_cmp/s_cbranch
        if (last || bend) {
            float* orow = out + ((size_t)n << 7) + (lane << 1);
            atomicAdd(orow,     accx);
            atomicAdd(orow + 1, accy);
            accx = 0.f; accy = 0.f;
            if (!last) {                        // advance to node owning e+1
                n++;
                nxt = __builtin_amdgcn_readfirstlane(
                    (n + 1 < N_NODES) ? off[n + 1] : N_EDGES);
                while (nxt <= e + 1) {          // skip empty nodes (rare)
                    n++;
                    nxt = __builtin_amdgcn_readfirstlane(
                        (n + 1 < N_NODES) ? off[n + 1] : N_EDGES);
                }
            }
        }
    };

    // batches 0..5 with 2-ahead prefetch; tail 6,7 drains
#pragma unroll 1
    for (int q = 0; q < 3; ++q) {
        const int base = q * 16;
        const int pb   = base + 16;             // refill with batch b+2
#pragma unroll
        for (int j = 0; j < 8; ++j) {
            edge_op(yA[j], base + j, false);
            int s = __builtin_amdgcn_readlane(src_l, pb + j);
            yA[j] = Yu[(size_t)s * 64 + lane];
        }
#pragma unroll
        for (int j = 0; j < 8; ++j) {
            edge_op(yB[j], base + 8 + j, false);
            int s = __builtin_amdgcn_readlane(src_l, pb + 8 + j);
            yB[j] = Yu[(size_t)s * 64 + lane];
        }
    }
#pragma unroll
    for (int j = 0; j < 8; ++j) edge_op(yA[j], 48 + j, false);
#pragma unroll
    for (int j = 0; j < 8; ++j) edge_op(yB[j], 56 + j, j == 7);
}

extern "C" void kernel_launch(void* const* d_in, const int* in_sizes, int n_in,
                              void* d_out, int out_size, void* d_ws, size_t ws_size,
                              hipStream_t stream) {
    const float* x     = (const float*)d_in[0];
    const int*   idx   = (const int*)  d_in[1];
    const float* ea    = (const float*)d_in[2];
    const float* gs    = (const float*)d_in[3];
    const float* Wneg  = (const float*)d_in[4];
    const float* bneg  = (const float*)d_in[5];
    const float* Wroot = (const float*)d_in[6];
    const float* broot = (const float*)d_in[7];
    float* out = (float*)d_out;

    // ws layout (16B-aligned sections):
    //   Yb      : N*128 bf16           25.6 MB
    //   cnt/off : N int each            0.8 MB
    //   bsum    : NBLK int (pad 2KB)
    //   pay     : E * 16B              25.6 MB
    //   rank    : E * 4B                6.4 MB
    //   Pneg/Proot : 40 KB each
    //   chunk_node : 25000 int         100 KB
    char* w = (char*)d_ws;
    __hip_bfloat16* Yb = (__hip_bfloat16*)w;      w += (size_t)N_NODES * 128 * 2;
    int* cnt  = (int*)w;                          w += (size_t)N_NODES * 4;
    int* off  = (int*)w;                          w += (size_t)N_NODES * 4;
    int* bsum = (int*)w;                          w += 2048;
    uint4* pay = (uint4*)w;                       w += (size_t)N_EDGES * 16;
    int* rank = (int*)w;                          w += (size_t)N_EDGES * 4;
    unsigned short* Pneg  = (unsigned short*)w;   w += (size_t)NKSTEP * 8 * 64 * 8 * 2;
    unsigned short* Proot = (unsigned short*)w;   w += (size_t)NKSTEP * 8 * 64 * 8 * 2;
    int* chunk_node = (int*)w;

    const int nb_edges = (N_EDGES + 255) / 256;

    repack_zero<<<80, 64, 0, stream>>>(Wneg, Wroot, Pneg, Proot, cnt);
    histogram_rank<<<nb_edges, 256, 0, stream>>>(idx, cnt, rank);
    scan_block_sums<<<NBLK, 256, 0, stream>>>(cnt, bsum);
    scan_final2<<<NBLK, 256, 0, stream>>>(cnt, bsum, off, chunk_node);
    gemm_scatter<<<2 * NGB, 256, 0, stream>>>(
        x, gs, Pneg, Proot, bneg, broot, Yb, out, idx, ea, off, rank, pay);
    aggregate<<<N_CHUNKS / 4, 256, 0, stream>>>(pay, Wneg, Yb, off, chunk_node, out);
}

// Round 13
// 404.699 us; speedup vs baseline: 1.1220x; 1.0070x over previous
//
#include <hip/hip_runtime.h>
#include <hip/hip_bf16.h>
#include <math.h>

#define N_NODES 100000
#define N_EDGES 1600000
#define IN_CH 128
#define OUT_CH 128
#define EDGE_DIM 6
#define STATE_DIM 5
#define XS_DIM 133          // IN_CH + STATE_DIM
#define KPAD 160            // 5 k-steps of 32
#define NKSTEP 5
#define ASTRIDE 168         // LDS row stride (bf16 elems)
#define NBLK 391            // ceil(N_NODES/256)
#define N_CHUNKS 25000      // N_EDGES / 64  (exact)
#define NGB 1563            // gemm blocks = ceil(N_NODES/64)
#define NHB 1601            // histogram role blocks in gemm_hist

typedef short s16x8 __attribute__((ext_vector_type(8)));
typedef float f32x4 __attribute__((ext_vector_type(4)));
typedef float f32x2 __attribute__((ext_vector_type(2)));
typedef unsigned u32x4 __attribute__((ext_vector_type(4)));

static __device__ __forceinline__ unsigned short f2bf(float f) {
    __hip_bfloat16 h = __float2bfloat16(f);   // RNE
    return *reinterpret_cast<unsigned short*>(&h);
}
static __device__ __forceinline__ float bflo(unsigned u) {   // low bf16 -> f32
    return __uint_as_float(u << 16);
}
static __device__ __forceinline__ float bfhi(unsigned u) {   // high bf16 -> f32
    return __uint_as_float(u & 0xffff0000u);
}

// ---------------------------------------------------------------------------
// repack_zero: W repack + cnt zeroing folded in. 80 blocks x 64.
// ---------------------------------------------------------------------------
__global__ __launch_bounds__(64) void repack_zero(
    const float* __restrict__ Wneg, const float* __restrict__ Wroot,
    unsigned short* __restrict__ Pneg, unsigned short* __restrict__ Proot,
    int* __restrict__ cnt)
{
    int b = blockIdx.x;
    int lane = threadIdx.x;

    // zero cnt: 5120 threads, 100000 ints -> ~20 per thread, coalesced
    for (int i = b * 64 + lane; i < N_NODES; i += 80 * 64) cnt[i] = 0;

    int mat = b / 40, r = b % 40;
    int kk = r / 8, nt = r % 8;
    const float* W = mat ? Wroot : Wneg;
    unsigned short* P = mat ? Proot : Pneg;
    int n = nt * 16 + (lane & 15);
    int kb = kk * 32 + (lane >> 4) * 8;
    unsigned short v[8];
#pragma unroll
    for (int j = 0; j < 8; ++j) {
        int k = kb + j;
        v[j] = (k < XS_DIM) ? f2bf(W[k * 128 + n]) : (unsigned short)0;
    }
    *(s16x8*)(P + ((size_t)(kk * 8 + nt) * 64 + lane) * 8) = *(s16x8*)v;
}

// ---------------------------------------------------------------------------
// gemm_hist: node GEMM blocks interleaved with histogram_rank blocks in ONE
// dispatch (role-split, no sync — R6's proven mechanism). Hypothesis: hist's
// atomic-with-return chain is the hidden ~100us whale in the serial CSR
// chain; hiding it under gemm's MFMA/LDS compute removes it from the
// critical path. Scatter (atomic-free since R10) runs standalone after.
//   blocks [0, 2*NGB): even -> gemm(bid/2), odd -> hist(bid/2)
//   blocks [2*NGB, 2*NGB + NHB-NGB): hist(NGB + bid - 2*NGB)
// ---------------------------------------------------------------------------
__global__ __launch_bounds__(256) void gemm_hist(
    const float* __restrict__ x, const float* __restrict__ gs,
    const unsigned short* __restrict__ Pneg, const unsigned short* __restrict__ Proot,
    const float* __restrict__ bneg, const float* __restrict__ broot,
    __hip_bfloat16* __restrict__ Yb, float* __restrict__ out,
    const int* __restrict__ idx, int* __restrict__ cnt, int* __restrict__ rank)
{
    __shared__ unsigned short Alds[64 * ASTRIDE];        // 21504 B
    __shared__ unsigned short Blds[2 * 8 * 64 * 8];      // 16384 B (per-kk slice)
    const int bid = blockIdx.x;
    int role, rid;
    if (bid < 2 * NGB) { role = bid & 1; rid = bid >> 1; }
    else               { role = 1;       rid = NGB + (bid - 2 * NGB); }
    const int tid = threadIdx.x;

    if (role == 1) {
        // ---- histogram with rank capture (grid-stride over edges) ----
        for (int e = rid * 256 + tid; e < N_EDGES; e += NHB * 256) {
            int d = __builtin_nontemporal_load(idx + e);
            int r = atomicAdd(&cnt[d], 1);
            __builtin_nontemporal_store(r, rank + e);
        }
        return;
    }

    // ---- node GEMM: 64 nodes, 4 waves ----
    const int lane = tid & 63;
    const int wv   = tid >> 6;
    const int n0   = rid * 64;

#pragma unroll
    for (int i = 0; i < 16; ++i) {
        int row = i * 4 + wv;
        int nn  = min(n0 + row, N_NODES - 1);
        const f32x2 v = __builtin_nontemporal_load(
            (const f32x2*)(x + (size_t)nn * IN_CH) + lane);
        unsigned pk = (unsigned)f2bf(v.x) | ((unsigned)f2bf(v.y) << 16);
        *(unsigned*)(&Alds[row * ASTRIDE + lane * 2]) = pk;   // aligned b32
    }
    // cols 128..159 (gs + zero pad): 64 rows x 16 u32-pairs, 4 per thread
#pragma unroll
    for (int s2 = 0; s2 < 4; ++s2) {
        int slot = tid * 4 + s2;        // 0..1023
        int row  = slot >> 4;
        int cp   = slot & 15;
        int nn   = min(n0 + row, N_NODES - 1);
        int c0   = IN_CH + cp * 2;
        unsigned lo = (c0     < XS_DIM) ? (unsigned)f2bf(gs[(size_t)nn * STATE_DIM + (c0 - IN_CH)])     : 0u;
        unsigned hi = (c0 + 1 < XS_DIM) ? (unsigned)f2bf(gs[(size_t)nn * STATE_DIM + (c0 + 1 - IN_CH)]) : 0u;
        *(unsigned*)(&Alds[row * ASTRIDE + c0]) = lo | (hi << 16);
    }

    f32x4 accN[8], accR[8];
    const f32x4 zero = {0.f, 0.f, 0.f, 0.f};
#pragma unroll
    for (int nt = 0; nt < 8; ++nt) { accN[nt] = zero; accR[nt] = zero; }

    const int m = lane & 15, quad = lane >> 4;
    const unsigned short* arow = Alds + (wv * 16 + m) * ASTRIDE + quad * 8;
    const unsigned short* bl   = Blds + lane * 8;          // (mat,nt) via offset

    for (int kk = 0; kk < NKSTEP; ++kk) {
        __syncthreads();      // kk=0: Alds ready; kk>0: prior Blds consumed
        // stage this kk's B slice: 1024 x 16B chunks, 4 per thread
#pragma unroll
        for (int j = 0; j < 4; ++j) {
            int c = tid * 4 + j;              // 0..1023
            int mat = c >> 9, r = c & 511;    // r = nt*64+lane
            const unsigned short* src =
                (mat ? Proot : Pneg) + ((size_t)(kk * 8) * 64 + r) * 8;
            *(s16x8*)(Blds + (size_t)c * 8) = *(const s16x8*)src;
        }
        __syncthreads();

        s16x8 a = *(const s16x8*)(arow + kk * 32);
#pragma unroll
        for (int nt = 0; nt < 8; ++nt) {
            s16x8 bn = *(const s16x8*)(bl + (size_t)nt * 512);          // mat 0
            accN[nt] = __builtin_amdgcn_mfma_f32_16x16x32_bf16(a, bn, accN[nt], 0, 0, 0);
            s16x8 br = *(const s16x8*)(bl + (size_t)(8 + nt) * 512);    // mat 1
            accR[nt] = __builtin_amdgcn_mfma_f32_16x16x32_bf16(a, br, accR[nt], 0, 0, 0);
        }
    }

#pragma unroll
    for (int nt = 0; nt < 8; ++nt) {
        int col = nt * 16 + m;
        float bn = bneg[col], br = broot[col];
        int rbase = n0 + wv * 16 + quad * 4;
#pragma unroll
        for (int r = 0; r < 4; ++r) {
            int node = rbase + r;
            if (node < N_NODES) {
                Yb[(size_t)node * 128 + col] = __float2bfloat16(accN[nt][r] + bn);
                float v = accR[nt][r] + br;
                out[(size_t)node * 128 + col] = (v > 0.f) ? v : (__expf(v) - 1.f);
            }
        }
    }
}

// ---------------------------------------------------------------------------
// Two-kernel scan (measured-best; R11's merged scan_all regressed 45us)
// ---------------------------------------------------------------------------
__global__ __launch_bounds__(256) void scan_block_sums(const int* __restrict__ cnt,
                                                       int* __restrict__ bsum) {
    __shared__ int ws[4];
    int tid = threadIdx.x, lane = tid & 63, wid = tid >> 6;
    int i = blockIdx.x * 256 + tid;
    int v = (i < N_NODES) ? cnt[i] : 0;
#pragma unroll
    for (int d = 32; d > 0; d >>= 1) v += __shfl_down(v, d);
    if (lane == 0) ws[wid] = v;
    __syncthreads();
    if (tid == 0) bsum[blockIdx.x] = ws[0] + ws[1] + ws[2] + ws[3];
}

// scan_final2: in-block 391-entry bsum prefix (NBLK ints only — cheap),
// node exclusive scan -> off, chunk_node fill.
__global__ __launch_bounds__(256) void scan_final2(const int* __restrict__ cnt,
                                                   const int* __restrict__ bsum,
                                                   int* __restrict__ off,
                                                   int* __restrict__ chunk_node) {
    __shared__ int wsum[4];
    __shared__ int bpre_s;
    int tid = threadIdx.x, lane = tid & 63, wid = tid >> 6;
    int bid = blockIdx.x;

    // block prefix = sum(bsum[0..bid))
    int pre = 0;
    for (int j = tid; j < bid; j += 256) pre += bsum[j];
#pragma unroll
    for (int d = 32; d > 0; d >>= 1) pre += __shfl_down(pre, d);
    if (lane == 0) wsum[wid] = pre;
    __syncthreads();
    if (tid == 0) bpre_s = wsum[0] + wsum[1] + wsum[2] + wsum[3];
    __syncthreads();
    int bpre = bpre_s;

    int i = bid * 256 + tid;
    int v = (i < N_NODES) ? cnt[i] : 0;
    int x = v;
#pragma unroll
    for (int d = 1; d < 64; d <<= 1) {
        int t = __shfl_up(x, d);
        if (lane >= d) x += t;
    }
    if (lane == 63) wsum[wid] = x;     // safe: all reads of phase-1 wsum done
    __syncthreads();
    int wpre = 0;
#pragma unroll
    for (int j = 0; j < 4; ++j) wpre += (j < wid) ? wsum[j] : 0;
    int excl = bpre + wpre + x - v;
    if (i < N_NODES) {
        off[i] = excl;
        if (v > 0) {
            int end = excl + v;
            for (int c = (excl + 63) >> 6; (c << 6) < end; ++c)
                chunk_node[c] = i;     // chunk start 64c lies inside [excl,end)
        }
    }
}

// ---------------------------------------------------------------------------
// scatter_edges: standalone fat grid, atomic-free (pos = off[dst]+rank[e]).
// ---------------------------------------------------------------------------
__global__ __launch_bounds__(256) void scatter_edges(
    const int* __restrict__ idx, const float* __restrict__ ea,
    const int* __restrict__ off, const int* __restrict__ rank,
    uint4* __restrict__ pay)
{
    int e = blockIdx.x * 256 + threadIdx.x;
    if (e < N_EDGES) {
        int dst = __builtin_nontemporal_load(idx + e);
        int src = __builtin_nontemporal_load(idx + N_EDGES + e);
        int rk  = __builtin_nontemporal_load(rank + e);
        const f32x2* er = (const f32x2*)(ea + (size_t)e * EDGE_DIM);
        f32x2 e01 = __builtin_nontemporal_load(er);
        f32x2 e23 = __builtin_nontemporal_load(er + 1);
        f32x2 e45 = __builtin_nontemporal_load(er + 2);
        unsigned p0 = (unsigned)f2bf(e01.x) | ((unsigned)f2bf(e01.y) << 16);
        unsigned p1 = (unsigned)f2bf(e23.x) | ((unsigned)f2bf(e23.y) << 16);
        unsigned p2 = (unsigned)f2bf(e45.x) | ((unsigned)f2bf(e45.y) << 16);
        int pos = off[dst] + rk;          // L2-resident read, no atomic
        u32x4 pl = { (unsigned)src, p0, p1, p2 };
        __builtin_nontemporal_store(pl, (u32x4*)pay + pos);
    }
}

// ---------------------------------------------------------------------------
// Aggregate, edge-parallel (R6 verbatim — measured best, 121+-2us band):
// ---------------------------------------------------------------------------
__global__ __launch_bounds__(256) void aggregate(
    const uint4* __restrict__ pay,
    const float* __restrict__ Wneg,  // bottom 6 rows at 133*128
    const __hip_bfloat16* __restrict__ Yb,
    const int* __restrict__ off,
    const int* __restrict__ chunk_node,
    float* __restrict__ out)
{
    const int lane = threadIdx.x & 63;
    const int wid  = __builtin_amdgcn_readfirstlane(blockIdx.x * 4 + (threadIdx.x >> 6));
    const int e0   = wid * 64;

    const float2* wb2 = (const float2*)(Wneg + 133 * 128);
    float2 wb[EDGE_DIM];
#pragma unroll
    for (int j = 0; j < EDGE_DIM; ++j) wb[j] = wb2[j * 64 + lane];

    const unsigned* Yu = (const unsigned*)Yb;   // 64 uints per row

    u32x4 pl = __builtin_nontemporal_load((const u32x4*)pay + e0 + lane);
    int src_l = (int)pl.x;
    int ea0 = (int)pl.y, ea1 = (int)pl.z, ea2 = (int)pl.w;

    // wave-uniform segment walk state
    int n   = __builtin_amdgcn_readfirstlane(chunk_node[wid]);
    int nxt = __builtin_amdgcn_readfirstlane((n + 1 < N_NODES) ? off[n + 1] : N_EDGES);

    float accx = 0.f, accy = 0.f;

    // prefetch batches 0 and 1 (16 Y-row loads in flight)
    unsigned yA[8], yB[8];
#pragma unroll
    for (int j = 0; j < 8; ++j) {
        int s = __builtin_amdgcn_readlane(src_l, j);
        yA[j] = Yu[(size_t)s * 64 + lane];
    }
#pragma unroll
    for (int j = 0; j < 8; ++j) {
        int s = __builtin_amdgcn_readlane(src_l, 8 + j);
        yB[j] = Yu[(size_t)s * 64 + lane];
    }

    auto edge_op = [&](unsigned yv, int c, bool last) {
        unsigned a0 = (unsigned)__builtin_amdgcn_readlane(ea0, c);
        unsigned a1 = (unsigned)__builtin_amdgcn_readlane(ea1, c);
        unsigned a2 = (unsigned)__builtin_amdgcn_readlane(ea2, c);
        float f0 = bflo(a0), f1 = bfhi(a0);
        float f2 = bflo(a1), f3 = bfhi(a1);
        float f4 = bflo(a2), f5 = bfhi(a2);
        float tx = bflo(yv), ty = bfhi(yv);
        tx = fmaf(f0, wb[0].x, tx); ty = fmaf(f0, wb[0].y, ty);
        tx = fmaf(f1, wb[1].x, tx); ty = fmaf(f1, wb[1].y, ty);
        tx = fmaf(f2, wb[2].x, tx); ty = fmaf(f2, wb[2].y, ty);
        tx = fmaf(f3, wb[3].x, tx); ty = fmaf(f3, wb[3].y, ty);
        tx = fmaf(f4, wb[4].x, tx); ty = fmaf(f4, wb[4].y, ty);
        tx = fmaf(f5, wb[5].x, tx); ty = fmaf(f5, wb[5].y, ty);
        tx = (tx > 0.f) ? tx : (__expf(tx) - 1.f);
        ty = (ty > 0.f) ? ty : (__expf(ty) - 1.f);
        accx += tx; accy += ty;
        int e = e0 + c;
        bool bend = (e + 1 == nxt);             // uniform -> s_cmp/s_cbranch
        if (last || bend) {
            float* orow = out + ((size_t)n << 7) + (lane << 1);
            atomicAdd(orow,     accx);
            atomicAdd(orow + 1, accy);
            accx = 0.f; accy = 0.f;
            if (!last) {                        // advance to node owning e+1
                n++;
                nxt = __builtin_amdgcn_readfirstlane(
                    (n + 1 < N_NODES) ? off[n + 1] : N_EDGES);
                while (nxt <= e + 1) {          // skip empty nodes (rare)
                    n++;
                    nxt = __builtin_amdgcn_readfirstlane(
                        (n + 1 < N_NODES) ? off[n + 1] : N_EDGES);
                }
            }
        }
    };

    // batches 0..5 with 2-ahead prefetch; tail 6,7 drains
#pragma unroll 1
    for (int q = 0; q < 3; ++q) {
        const int base = q * 16;
        const int pb   = base + 16;             // refill with batch b+2
#pragma unroll
        for (int j = 0; j < 8; ++j) {
            edge_op(yA[j], base + j, false);
            int s = __builtin_amdgcn_readlane(src_l, pb + j);
            yA[j] = Yu[(size_t)s * 64 + lane];
        }
#pragma unroll
        for (int j = 0; j < 8; ++j) {
            edge_op(yB[j], base + 8 + j, false);
            int s = __builtin_amdgcn_readlane(src_l, pb + 8 + j);
            yB[j] = Yu[(size_t)s * 64 + lane];
        }
    }
#pragma unroll
    for (int j = 0; j < 8; ++j) edge_op(yA[j], 48 + j, false);
#pragma unroll
    for (int j = 0; j < 8; ++j) edge_op(yB[j], 56 + j, j == 7);
}

extern "C" void kernel_launch(void* const* d_in, const int* in_sizes, int n_in,
                              void* d_out, int out_size, void* d_ws, size_t ws_size,
                              hipStream_t stream) {
    const float* x     = (const float*)d_in[0];
    const int*   idx   = (const int*)  d_in[1];
    const float* ea    = (const float*)d_in[2];
    const float* gs    = (const float*)d_in[3];
    const float* Wneg  = (const float*)d_in[4];
    const float* bneg  = (const float*)d_in[5];
    const float* Wroot = (const float*)d_in[6];
    const float* broot = (const float*)d_in[7];
    float* out = (float*)d_out;

    // ws layout (16B-aligned sections):
    //   Yb      : N*128 bf16           25.6 MB
    //   cnt/off : N int each            0.8 MB
    //   bsum    : NBLK int (pad 2KB)
    //   pay     : E * 16B              25.6 MB
    //   rank    : E * 4B                6.4 MB
    //   Pneg/Proot : 40 KB each
    //   chunk_node : 25000 int         100 KB
    char* w = (char*)d_ws;
    __hip_bfloat16* Yb = (__hip_bfloat16*)w;      w += (size_t)N_NODES * 128 * 2;
    int* cnt  = (int*)w;                          w += (size_t)N_NODES * 4;
    int* off  = (int*)w;                          w += (size_t)N_NODES * 4;
    int* bsum = (int*)w;                          w += 2048;
    uint4* pay = (uint4*)w;                       w += (size_t)N_EDGES * 16;
    int* rank = (int*)w;                          w += (size_t)N_EDGES * 4;
    unsigned short* Pneg  = (unsigned short*)w;   w += (size_t)NKSTEP * 8 * 64 * 8 * 2;
    unsigned short* Proot = (unsigned short*)w;   w += (size_t)NKSTEP * 8 * 64 * 8 * 2;
    int* chunk_node = (int*)w;

    const int nb_edges = (N_EDGES + 255) / 256;

    repack_zero<<<80, 64, 0, stream>>>(Wneg, Wroot, Pneg, Proot, cnt);
    gemm_hist<<<2 * NGB + (NHB - NGB), 256, 0, stream>>>(
        x, gs, Pneg, Proot, bneg, broot, Yb, out, idx, cnt, rank);
    scan_block_sums<<<NBLK, 256, 0, stream>>>(cnt, bsum);
    scan_final2<<<NBLK, 256, 0, stream>>>(cnt, bsum, off, chunk_node);
    scatter_edges<<<nb_edges, 256, 0, stream>>>(idx, ea, off, rank, pay);
    aggregate<<<N_CHUNKS / 4, 256, 0, stream>>>(pay, Wneg, Yb, off, chunk_node, out);
}